// Round 1
// baseline (674.679 us; speedup 1.0000x reference)
//
#include <hip/hip_runtime.h>
#include <cmath>

// Problem constants (B, N, F_IN, M, U) = (2, 2048, 128, 8, 64)
#define B_ 2
#define N_ 2048
#define F_ 128
#define M_ 8
#define U_ 64

// -------------------------------------------------------------------------
// k_beta: beta_t[b][u][n] = sum_f seq[b,n,f] * ew[f,u]   (stored TRANSPOSED
// so k_main can ds_read_b128 along j). grid (64,4), block 256.
// Each block stages 64 seq rows in LDS (lane = row), computes 16 u columns.
// -------------------------------------------------------------------------
__global__ __launch_bounds__(256) void k_beta(const float* __restrict__ seq,
                                              const float* __restrict__ ew,
                                              float* __restrict__ beta_t) {
  __shared__ float s_tile[64][129];  // +1 pad: (lane*129+f)%32 = (lane+f)%32, 2-way free
  const int t    = threadIdx.x;
  const int lane = t & 63;
  const int wave = __builtin_amdgcn_readfirstlane(t >> 6);  // 0..3
  const int row0 = blockIdx.x * 64;

  const float4* seq4 = (const float4*)(seq + (size_t)row0 * F_);
#pragma unroll
  for (int k = 0; k < 8; ++k) {
    int idx = t + k * 256;          // 0..2047 float4s, coalesced
    int r = idx >> 5, f4 = idx & 31;
    float4 v = seq4[idx];
    s_tile[r][f4 * 4 + 0] = v.x; s_tile[r][f4 * 4 + 1] = v.y;
    s_tile[r][f4 * 4 + 2] = v.z; s_tile[r][f4 * 4 + 3] = v.w;
  }
  __syncthreads();

  const int u_base = blockIdx.y * 16 + wave * 4;  // 16 u per block, 4 per wave
  float a0 = 0.f, a1 = 0.f, a2 = 0.f, a3 = 0.f;
#pragma unroll 4
  for (int f = 0; f < F_; ++f) {
    float s  = s_tile[lane][f];                       // lane = row
    float4 w = *(const float4*)(ew + f * U_ + u_base); // wave-uniform addr
    a0 = fmaf(s, w.x, a0); a1 = fmaf(s, w.y, a1);
    a2 = fmaf(s, w.z, a2); a3 = fmaf(s, w.w, a3);
  }
  const int grow = row0 + lane;                // global row = b*N + n
  const int b = grow >> 11, n = grow & (N_ - 1);
  float* dst = beta_t + ((size_t)(b * U_ + u_base)) * N_ + n;  // coalesced over lanes
  dst[0]             = a0;
  dst[(size_t)N_]    = a1;
  dst[(size_t)2 * N_] = a2;
  dst[(size_t)3 * N_] = a3;
}

// -------------------------------------------------------------------------
// k_alpha: out[b,n,m,u] = sum_f seq[b,n,f] * vw[f,m,u]   (PRE-activation,
// written into d_out; k_main adds the graph term and applies sigmoid).
// grid 512, block 256; wave <-> 2 rows, lane = u, acc[2][8].
// -------------------------------------------------------------------------
__global__ __launch_bounds__(256) void k_alpha(const float* __restrict__ seq,
                                               const float* __restrict__ vw,
                                               float* __restrict__ out) {
  const int t    = threadIdx.x;
  const int lane = t & 63;
  const int wave = __builtin_amdgcn_readfirstlane(t >> 6);  // 0..3
  const int r0   = blockIdx.x * 8 + wave * 2;               // global row pair

  const float* s0 = seq + (size_t)r0 * F_;
  const float* s1 = s0 + F_;
  float acc0[8] = {0, 0, 0, 0, 0, 0, 0, 0};
  float acc1[8] = {0, 0, 0, 0, 0, 0, 0, 0};
  const float* w = vw + lane;
#pragma unroll 4
  for (int f = 0; f < F_; ++f) {
    float sa = s0[f], sb = s1[f];            // wave-uniform
    const float* wf = w + (size_t)f * (M_ * U_);
#pragma unroll
    for (int m = 0; m < 8; ++m) {
      float wv = wf[m * 64];                 // coalesced over lanes
      acc0[m] = fmaf(sa, wv, acc0[m]);
      acc1[m] = fmaf(sb, wv, acc1[m]);
    }
  }
  float* o = out + (size_t)r0 * (M_ * U_) + lane;
#pragma unroll
  for (int m = 0; m < 8; ++m) {
    o[m * 64]       = acc0[m];
    o[512 + m * 64] = acc1[m];
  }
}

// -------------------------------------------------------------------------
// k_main: out[b,i,m,u] = sigmoid( sum_j graph[b,i,j,m]*beta[b,j,u] + out )
// grid 1024, block 128 (2 waves); wave <-> 2 rows, lane = u.
// Beta chunk (128 j) staged in LDS layout [u][j], stride 132 (==4 mod 32 ->
// canonical conflict-free b128 pattern). Graph loads are wave-uniform
// float4s (scalar-promotable). Per 4-j step: 1 ds_read_b128 + 64 FMA.
// -------------------------------------------------------------------------
__global__ __launch_bounds__(128, 2) void k_main(const float* __restrict__ graph,
                                                 const float* __restrict__ beta_t,
                                                 float* __restrict__ out) {
  __shared__ float lds[64 * 132];  // 33792 B -> 4 wg/CU
  const int t    = threadIdx.x;
  const int lane = t & 63;
  const int wave = __builtin_amdgcn_readfirstlane(t >> 6);  // 0..1
  const int r0   = blockIdx.x * 4 + wave * 2;               // global row = b*N + i
  const int b    = r0 >> 11;

  const float* g0 = graph + (size_t)r0 * (N_ * M_);  // (b*N+i)*N*M
  const float* g1 = g0 + N_ * M_;
  const float* bt = beta_t + (size_t)b * (U_ * N_);

  float acc0[8] = {0, 0, 0, 0, 0, 0, 0, 0};
  float acc1[8] = {0, 0, 0, 0, 0, 0, 0, 0};

  for (int c = 0; c < N_ / 128; ++c) {
    const int j0 = c * 128;
    __syncthreads();  // protect LDS readers of previous chunk
#pragma unroll
    for (int k = 0; k < 16; ++k) {
      int idx = t + k * 128;        // 0..2047 float4s of the 64x128 chunk
      int ur = idx >> 5, j4 = idx & 31;
      float4 v = *(const float4*)(bt + (size_t)ur * N_ + j0 + j4 * 4);
      *(float4*)&lds[ur * 132 + j4 * 4] = v;
    }
    __syncthreads();

    const float4* ga = (const float4*)(g0 + (size_t)j0 * M_);
    const float4* gb = (const float4*)(g1 + (size_t)j0 * M_);
#pragma unroll 2
    for (int j4 = 0; j4 < 32; ++j4) {
      float4 bv = *(const float4*)&lds[lane * 132 + j4 * 4];
#pragma unroll
      for (int jj = 0; jj < 4; ++jj) {
        const float bj = (jj == 0) ? bv.x : (jj == 1) ? bv.y : (jj == 2) ? bv.z : bv.w;
        float4 pa = ga[(j4 * 4 + jj) * 2 + 0];
        float4 pb = ga[(j4 * 4 + jj) * 2 + 1];
        float4 qa = gb[(j4 * 4 + jj) * 2 + 0];
        float4 qb = gb[(j4 * 4 + jj) * 2 + 1];
        acc0[0] = fmaf(pa.x, bj, acc0[0]); acc0[1] = fmaf(pa.y, bj, acc0[1]);
        acc0[2] = fmaf(pa.z, bj, acc0[2]); acc0[3] = fmaf(pa.w, bj, acc0[3]);
        acc0[4] = fmaf(pb.x, bj, acc0[4]); acc0[5] = fmaf(pb.y, bj, acc0[5]);
        acc0[6] = fmaf(pb.z, bj, acc0[6]); acc0[7] = fmaf(pb.w, bj, acc0[7]);
        acc1[0] = fmaf(qa.x, bj, acc1[0]); acc1[1] = fmaf(qa.y, bj, acc1[1]);
        acc1[2] = fmaf(qa.z, bj, acc1[2]); acc1[3] = fmaf(qa.w, bj, acc1[3]);
        acc1[4] = fmaf(qb.x, bj, acc1[4]); acc1[5] = fmaf(qb.y, bj, acc1[5]);
        acc1[6] = fmaf(qb.z, bj, acc1[6]); acc1[7] = fmaf(qb.w, bj, acc1[7]);
      }
    }
  }

  // Epilogue: add alpha (pre-written into d_out by k_alpha), sigmoid, store.
  float* o = out + (size_t)r0 * (M_ * U_) + lane;
#pragma unroll
  for (int m = 0; m < 8; ++m) {
    float x0 = acc0[m] + o[m * 64];
    float x1 = acc1[m] + o[512 + m * 64];
    o[m * 64]       = 1.0f / (1.0f + __expf(-x0));
    o[512 + m * 64] = 1.0f / (1.0f + __expf(-x1));
  }
}

// -------------------------------------------------------------------------
extern "C" void kernel_launch(void* const* d_in, const int* in_sizes, int n_in,
                              void* d_out, int out_size, void* d_ws, size_t ws_size,
                              hipStream_t stream) {
  const float* seq   = (const float*)d_in[0];  // (B,N,F)
  const float* graph = (const float*)d_in[1];  // (B,N,N,M)
  const float* ew    = (const float*)d_in[2];  // (F,U)
  const float* vw    = (const float*)d_in[3];  // (F,M,U)
  float* out = (float*)d_out;                  // (B,N,M,U)
  float* beta_t = (float*)d_ws;                // [B][U][N] = 1 MB scratch

  hipLaunchKernelGGL(k_beta,  dim3(64, 4), dim3(256), 0, stream, seq, ew, beta_t);
  hipLaunchKernelGGL(k_alpha, dim3(512),   dim3(256), 0, stream, seq, vw, out);
  hipLaunchKernelGGL(k_main,  dim3(1024),  dim3(128), 0, stream, graph, beta_t, out);
}

// Round 2
// 555.467 us; speedup vs baseline: 1.2146x; 1.2146x over previous
//
#include <hip/hip_runtime.h>
#include <cmath>

// (B, N, F_IN, M, U) = (2, 2048, 128, 8, 64)
#define N_ 2048
#define F_ 128
#define M_ 8
#define U_ 64

// -------------------------------------------------------------------------
// k_beta: beta[b][n][u] = sum_f seq[b,n,f] * ew[f,u]  (NATURAL layout now —
// k_main wants B_tile[j][u] rows contiguous in u).
// grid 256, block 256 (4 waves); 16 rows/block staged in LDS; lane = u.
// ew loads are lane-parallel (coalesced, L1-hot: ew = 32 KB).
// -------------------------------------------------------------------------
__global__ __launch_bounds__(256) void k_beta(const float* __restrict__ seq,
                                              const float* __restrict__ ew,
                                              float* __restrict__ beta) {
  __shared__ float st[16 * 132];
  const int t    = threadIdx.x;
  const int lane = t & 63;
  const int wv   = t >> 6;
  const int row0 = blockIdx.x * 16;
#pragma unroll
  for (int k = 0; k < 2; ++k) {
    int id = t + k * 256;                    // 512 float4s of 16x128 tile
    int r = id >> 5, f4 = id & 31;
    float4 v = *(const float4*)(seq + (size_t)(row0 + r) * F_ + f4 * 4);
    *(float4*)&st[r * 132 + f4 * 4] = v;
  }
  __syncthreads();
  const int r0 = wv * 4;
  float acc[4] = {0.f, 0.f, 0.f, 0.f};
#pragma unroll 8
  for (int f = 0; f < F_; ++f) {
    float e = ew[f * U_ + lane];             // lane-parallel, coalesced
#pragma unroll
    for (int r = 0; r < 4; ++r)
      acc[r] = fmaf(st[(r0 + r) * 132 + f], e, acc[r]);
  }
#pragma unroll
  for (int r = 0; r < 4; ++r)
    beta[(size_t)(row0 + r0 + r) * U_ + lane] = acc[r];
}

// -------------------------------------------------------------------------
// k_alpha: out[b,n,m,u] = sum_f seq[b,n,f] * vw[f,m,u]  (pre-activation into
// d_out; k_main adds graph term + sigmoid). grid 256, block 256 (4 waves);
// 16 rows/block via LDS; lane = u; vw loads lane-parallel (L1/L2-hot).
// -------------------------------------------------------------------------
__global__ __launch_bounds__(256) void k_alpha(const float* __restrict__ seq,
                                               const float* __restrict__ vw,
                                               float* __restrict__ out) {
  __shared__ float st[16 * 132];
  const int t    = threadIdx.x;
  const int lane = t & 63;
  const int wv   = t >> 6;
  const int row0 = blockIdx.x * 16;
#pragma unroll
  for (int k = 0; k < 2; ++k) {
    int id = t + k * 256;
    int r = id >> 5, f4 = id & 31;
    float4 v = *(const float4*)(seq + (size_t)(row0 + r) * F_ + f4 * 4);
    *(float4*)&st[r * 132 + f4 * 4] = v;
  }
  __syncthreads();
  const int r0 = wv * 4;
  float acc[4][8] = {};
  const float* w = vw + lane;
#pragma unroll 2
  for (int f = 0; f < F_; ++f) {
    float s0 = st[(r0 + 0) * 132 + f];
    float s1 = st[(r0 + 1) * 132 + f];
    float s2 = st[(r0 + 2) * 132 + f];
    float s3 = st[(r0 + 3) * 132 + f];
#pragma unroll
    for (int m = 0; m < 8; ++m) {
      float wvv = w[(size_t)(f * 8 + m) * 64];  // lane-parallel, coalesced
      acc[0][m] = fmaf(s0, wvv, acc[0][m]);
      acc[1][m] = fmaf(s1, wvv, acc[1][m]);
      acc[2][m] = fmaf(s2, wvv, acc[2][m]);
      acc[3][m] = fmaf(s3, wvv, acc[3][m]);
    }
  }
#pragma unroll
  for (int r = 0; r < 4; ++r) {
    float* o = out + (size_t)(row0 + r0 + r) * (M_ * U_) + lane;
#pragma unroll
    for (int m = 0; m < 8; ++m) o[m * 64] = acc[r][m];
  }
}

// -------------------------------------------------------------------------
// k_main: GEMM framing per batch b: C[r=i*8+m][u] = sum_j A[r][j]*B[j][u],
// A[r][j] = graph[b,i,j,m], B = beta. R=16384, U=64, K=2048.
// Block = 64 r x 64 u tile, 256 threads (4 waves), thread tile 4m x 4u.
// A is LANE-PARALLEL direct from global: thread reads graph[b][i][j][m0:4]
// as one float4 per j (4 distinct 32B segments/wave-inst; consecutive j
// sweep cache lines -> full HBM line consumption, ~4.9 TB/s sustainable).
// B tile (128 j x 64 u) staged in LDS; inner read = b128, 16 distinct
// addresses x4 dup = 2-way/bank = free.
// grid 512 (= 256 r-tiles x 2 b) -> 2 blocks/CU (LDS 34.8 KB), 8 waves/CU.
// -------------------------------------------------------------------------
__global__ __launch_bounds__(256, 2) void k_main(const float* __restrict__ graph,
                                                 const float* __restrict__ beta,
                                                 float* __restrict__ out) {
  __shared__ float Bt[128 * 68];             // 34816 B
  const int t  = threadIdx.x;
  const int tr = t >> 4;                     // 0..15 -> (i, m-half)
  const int tu = t & 15;                     // 0..15 -> u quad
  const int bx = blockIdx.x;
  const int b  = bx >> 8;
  const int rb = bx & 255;                   // 64-row tile; i0 = rb*8
  const int i  = rb * 8 + (tr >> 1);
  const int m0 = (tr & 1) * 4;
  const int u0 = tu * 4;

  const float* gp = graph + ((size_t)(b * N_ + i) * N_) * M_ + m0;
  const float* bp = beta + (size_t)b * N_ * U_;

  float acc[4][4] = {};                      // [m][u]

  for (int c = 0; c < N_ / 128; ++c) {
    const int j0 = c * 128;
    __syncthreads();                         // previous-chunk readers done
#pragma unroll
    for (int k = 0; k < 8; ++k) {
      int id = t + k * 256;                  // 2048 float4s of 128x64 B-tile
      int jj = id >> 4, uu = id & 15;
      float4 v = *(const float4*)(bp + (size_t)(j0 + jj) * U_ + uu * 4);
      *(float4*)&Bt[jj * 68 + uu * 4] = v;
    }
    __syncthreads();

#pragma unroll 8
    for (int j = 0; j < 128; ++j) {
      float4 a  = *(const float4*)(gp + (size_t)(j0 + j) * M_);
      float4 bv = *(const float4*)&Bt[j * 68 + u0];
      acc[0][0] = fmaf(a.x, bv.x, acc[0][0]);
      acc[0][1] = fmaf(a.x, bv.y, acc[0][1]);
      acc[0][2] = fmaf(a.x, bv.z, acc[0][2]);
      acc[0][3] = fmaf(a.x, bv.w, acc[0][3]);
      acc[1][0] = fmaf(a.y, bv.x, acc[1][0]);
      acc[1][1] = fmaf(a.y, bv.y, acc[1][1]);
      acc[1][2] = fmaf(a.y, bv.z, acc[1][2]);
      acc[1][3] = fmaf(a.y, bv.w, acc[1][3]);
      acc[2][0] = fmaf(a.z, bv.x, acc[2][0]);
      acc[2][1] = fmaf(a.z, bv.y, acc[2][1]);
      acc[2][2] = fmaf(a.z, bv.z, acc[2][2]);
      acc[2][3] = fmaf(a.z, bv.w, acc[2][3]);
      acc[3][0] = fmaf(a.w, bv.x, acc[3][0]);
      acc[3][1] = fmaf(a.w, bv.y, acc[3][1]);
      acc[3][2] = fmaf(a.w, bv.z, acc[3][2]);
      acc[3][3] = fmaf(a.w, bv.w, acc[3][3]);
    }
  }

  // Epilogue: rows r = rb*64 + tr*4 + mm (mm=0..3), add alpha, sigmoid.
  const int rbase = rb * 64 + tr * 4;
  float* o = out + (size_t)(b * 16384 + rbase) * U_ + u0;
#pragma unroll
  for (int mm = 0; mm < 4; ++mm) {
    float4 al = *(float4*)(o + (size_t)mm * U_);
    float4 res;
    res.x = 1.0f / (1.0f + __expf(-(acc[mm][0] + al.x)));
    res.y = 1.0f / (1.0f + __expf(-(acc[mm][1] + al.y)));
    res.z = 1.0f / (1.0f + __expf(-(acc[mm][2] + al.z)));
    res.w = 1.0f / (1.0f + __expf(-(acc[mm][3] + al.w)));
    *(float4*)(o + (size_t)mm * U_) = res;
  }
}

// -------------------------------------------------------------------------
extern "C" void kernel_launch(void* const* d_in, const int* in_sizes, int n_in,
                              void* d_out, int out_size, void* d_ws, size_t ws_size,
                              hipStream_t stream) {
  const float* seq   = (const float*)d_in[0];  // (B,N,F)
  const float* graph = (const float*)d_in[1];  // (B,N,N,M)
  const float* ew    = (const float*)d_in[2];  // (F,U)
  const float* vw    = (const float*)d_in[3];  // (F,M,U)
  float* out  = (float*)d_out;                 // (B,N,M,U)
  float* beta = (float*)d_ws;                  // [B][N][U] = 1 MB scratch

  hipLaunchKernelGGL(k_beta,  dim3(256), dim3(256), 0, stream, seq, ew, beta);
  hipLaunchKernelGGL(k_alpha, dim3(256), dim3(256), 0, stream, seq, vw, out);
  hipLaunchKernelGGL(k_main,  dim3(512), dim3(256), 0, stream, graph, beta, out);
}

// Round 3
// 548.892 us; speedup vs baseline: 1.2292x; 1.0120x over previous
//
#include <hip/hip_runtime.h>
#include <cmath>

// (B, N, F_IN, M, U) = (2, 2048, 128, 8, 64)
#define N_ 2048
#define F_ 128
#define M_ 8
#define U_ 64

// -------------------------------------------------------------------------
// k_beta: beta[b][n][u] = sum_f seq[b,n,f] * ew[f,u]
// grid 256, block 256 (4 waves); 16 rows/block staged in LDS; lane = u.
// -------------------------------------------------------------------------
__global__ __launch_bounds__(256) void k_beta(const float* __restrict__ seq,
                                              const float* __restrict__ ew,
                                              float* __restrict__ beta) {
  __shared__ float st[16 * 132];
  const int t    = threadIdx.x;
  const int lane = t & 63;
  const int wv   = t >> 6;
  const int row0 = blockIdx.x * 16;
#pragma unroll
  for (int k = 0; k < 2; ++k) {
    int id = t + k * 256;                    // 512 float4s of 16x128 tile
    int r = id >> 5, f4 = id & 31;
    float4 v = *(const float4*)(seq + (size_t)(row0 + r) * F_ + f4 * 4);
    *(float4*)&st[r * 132 + f4 * 4] = v;
  }
  __syncthreads();
  const int r0 = wv * 4;
  float acc[4] = {0.f, 0.f, 0.f, 0.f};
#pragma unroll 8
  for (int f = 0; f < F_; ++f) {
    float e = ew[f * U_ + lane];             // lane-parallel, coalesced
#pragma unroll
    for (int r = 0; r < 4; ++r)
      acc[r] = fmaf(st[(r0 + r) * 132 + f], e, acc[r]);
  }
#pragma unroll
  for (int r = 0; r < 4; ++r)
    beta[(size_t)(row0 + r0 + r) * U_ + lane] = acc[r];
}

// -------------------------------------------------------------------------
// k_alpha: out[b,n,m,u] = sum_f seq[b,n,f] * vw[f,m,u]  (pre-activation into
// d_out; k_main adds graph term + sigmoid). grid 256, block 256 (4 waves);
// 16 rows/block via LDS; lane = u; vw loads lane-parallel (L2-hot, 256 KB).
// -------------------------------------------------------------------------
__global__ __launch_bounds__(256) void k_alpha(const float* __restrict__ seq,
                                               const float* __restrict__ vw,
                                               float* __restrict__ out) {
  __shared__ float st[16 * 132];
  const int t    = threadIdx.x;
  const int lane = t & 63;
  const int wv   = t >> 6;
  const int row0 = blockIdx.x * 16;
#pragma unroll
  for (int k = 0; k < 2; ++k) {
    int id = t + k * 256;
    int r = id >> 5, f4 = id & 31;
    float4 v = *(const float4*)(seq + (size_t)(row0 + r) * F_ + f4 * 4);
    *(float4*)&st[r * 132 + f4 * 4] = v;
  }
  __syncthreads();
  const int r0 = wv * 4;
  float acc[4][8] = {};
  const float* w = vw + lane;
#pragma unroll 2
  for (int f = 0; f < F_; ++f) {
    float s0 = st[(r0 + 0) * 132 + f];
    float s1 = st[(r0 + 1) * 132 + f];
    float s2 = st[(r0 + 2) * 132 + f];
    float s3 = st[(r0 + 3) * 132 + f];
#pragma unroll
    for (int m = 0; m < 8; ++m) {
      float wvv = w[(size_t)(f * 8 + m) * 64];  // lane-parallel, coalesced
      acc[0][m] = fmaf(s0, wvv, acc[0][m]);
      acc[1][m] = fmaf(s1, wvv, acc[1][m]);
      acc[2][m] = fmaf(s2, wvv, acc[2][m]);
      acc[3][m] = fmaf(s3, wvv, acc[3][m]);
    }
  }
#pragma unroll
  for (int r = 0; r < 4; ++r) {
    float* o = out + (size_t)(row0 + r0 + r) * (M_ * U_) + lane;
#pragma unroll
    for (int m = 0; m < 8; ++m) o[m * 64] = acc[r][m];
  }
}

// -------------------------------------------------------------------------
// k_main: per batch b: C[r=i*8+m][u] = sum_j A[r][j]*B[j][u],
// A[r][j] = graph[b,i,j,m], B = beta. R=16384, U=64, K=2048.
//
// Lane map (round-3 fix — maximize useful bytes per A-load instruction):
//   wave w = t>>6 (0..3) -> u-group w*16
//   rr = (t&63)>>2 (0..15) -> (i_loc = rr>>1, mhalf = rr&1)
//   uq = t&3 -> u0 = w*16 + uq*4
// Per A-load wave-inst: 16 DISTINCT float4 addrs (8x32B contiguous
// segments) = 256 B useful (was 64 B with the tu-major map). 4 lanes/addr
// broadcast = free. B ds_read_b128: 4 distinct addrs over 16 consecutive
// banks, 16-way broadcast -> conflict-free.
// Block = 64 rows x 64 u, grid 512 (2 blocks/CU, 8 waves/CU).
// -------------------------------------------------------------------------
__global__ __launch_bounds__(256, 2) void k_main(const float* __restrict__ graph,
                                                 const float* __restrict__ beta,
                                                 float* __restrict__ out) {
  __shared__ float Bt[128 * 68];             // 34816 B
  const int t    = threadIdx.x;
  const int w    = t >> 6;
  const int lane = t & 63;
  const int rr   = lane >> 2;                // 0..15
  const int uq   = lane & 3;                 // 0..3
  const int i_loc = rr >> 1;                 // 0..7
  const int mh    = rr & 1;                  // 0..1
  const int u0    = w * 16 + uq * 4;

  const int bx = blockIdx.x;
  const int b  = bx >> 8;
  const int rb = bx & 255;                   // 64-row tile; i0 = rb*8
  const int i  = rb * 8 + i_loc;

  const float* gp = graph + ((size_t)(b * N_ + i) * N_) * M_ + mh * 4;
  const float* bp = beta + (size_t)b * N_ * U_;

  float acc[4][4] = {};                      // [mm][uu], m = mh*4+mm

  for (int c = 0; c < N_ / 128; ++c) {
    const int j0 = c * 128;
    __syncthreads();                         // previous-chunk readers done
#pragma unroll
    for (int k = 0; k < 8; ++k) {
      int id = t + k * 256;                  // 2048 float4s of 128x64 B-tile
      int jj = id >> 4, uu = id & 15;
      float4 v = *(const float4*)(bp + (size_t)(j0 + jj) * U_ + uu * 4);
      *(float4*)&Bt[jj * 68 + uu * 4] = v;
    }
    __syncthreads();

#pragma unroll 8
    for (int j = 0; j < 128; ++j) {
      float4 a  = *(const float4*)(gp + (size_t)(j0 + j) * M_);
      float4 bv = *(const float4*)&Bt[j * 68 + u0];
      acc[0][0] = fmaf(a.x, bv.x, acc[0][0]);
      acc[0][1] = fmaf(a.x, bv.y, acc[0][1]);
      acc[0][2] = fmaf(a.x, bv.z, acc[0][2]);
      acc[0][3] = fmaf(a.x, bv.w, acc[0][3]);
      acc[1][0] = fmaf(a.y, bv.x, acc[1][0]);
      acc[1][1] = fmaf(a.y, bv.y, acc[1][1]);
      acc[1][2] = fmaf(a.y, bv.z, acc[1][2]);
      acc[1][3] = fmaf(a.y, bv.w, acc[1][3]);
      acc[2][0] = fmaf(a.z, bv.x, acc[2][0]);
      acc[2][1] = fmaf(a.z, bv.y, acc[2][1]);
      acc[2][2] = fmaf(a.z, bv.z, acc[2][2]);
      acc[2][3] = fmaf(a.z, bv.w, acc[2][3]);
      acc[3][0] = fmaf(a.w, bv.x, acc[3][0]);
      acc[3][1] = fmaf(a.w, bv.y, acc[3][1]);
      acc[3][2] = fmaf(a.w, bv.z, acc[3][2]);
      acc[3][3] = fmaf(a.w, bv.w, acc[3][3]);
    }
  }

  // Epilogue: row = rb*64 + i_loc*8 + mh*4 + mm; add alpha, sigmoid.
  float* o = out + ((size_t)(b * 16384 + rb * 64 + i_loc * 8 + mh * 4)) * U_ + u0;
#pragma unroll
  for (int mm = 0; mm < 4; ++mm) {
    float4 al = *(float4*)(o + (size_t)mm * U_);
    float4 res;
    res.x = 1.0f / (1.0f + __expf(-(acc[mm][0] + al.x)));
    res.y = 1.0f / (1.0f + __expf(-(acc[mm][1] + al.y)));
    res.z = 1.0f / (1.0f + __expf(-(acc[mm][2] + al.z)));
    res.w = 1.0f / (1.0f + __expf(-(acc[mm][3] + al.w)));
    *(float4*)(o + (size_t)mm * U_) = res;
  }
}

// -------------------------------------------------------------------------
extern "C" void kernel_launch(void* const* d_in, const int* in_sizes, int n_in,
                              void* d_out, int out_size, void* d_ws, size_t ws_size,
                              hipStream_t stream) {
  const float* seq   = (const float*)d_in[0];  // (B,N,F)
  const float* graph = (const float*)d_in[1];  // (B,N,N,M)
  const float* ew    = (const float*)d_in[2];  // (F,U)
  const float* vw    = (const float*)d_in[3];  // (F,M,U)
  float* out  = (float*)d_out;                 // (B,N,M,U)
  float* beta = (float*)d_ws;                  // [B][N][U] = 1 MB scratch

  hipLaunchKernelGGL(k_beta,  dim3(256), dim3(256), 0, stream, seq, ew, beta);
  hipLaunchKernelGGL(k_alpha, dim3(256), dim3(256), 0, stream, seq, vw, out);
  hipLaunchKernelGGL(k_main,  dim3(512), dim3(256), 0, stream, graph, beta, out);
}

// Round 4
// 543.023 us; speedup vs baseline: 1.2424x; 1.0108x over previous
//
#include <hip/hip_runtime.h>
#include <cmath>

// (B, N, F_IN, M, U) = (2, 2048, 128, 8, 64)
#define N_ 2048
#define F_ 128
#define M_ 8
#define U_ 64

// -------------------------------------------------------------------------
// k_beta: beta[b][n][u] = sum_f seq[b,n,f] * ew[f,u]
// grid 256, block 256 (4 waves); 16 rows/block staged in LDS; lane = u.
// Small (67 MFLOP, 2 MB reads) — not on the critical path.
// -------------------------------------------------------------------------
__global__ __launch_bounds__(256) void k_beta(const float* __restrict__ seq,
                                              const float* __restrict__ ew,
                                              float* __restrict__ beta) {
  __shared__ float st[16 * 132];
  const int t    = threadIdx.x;
  const int lane = t & 63;
  const int wv   = t >> 6;
  const int row0 = blockIdx.x * 16;
#pragma unroll
  for (int k = 0; k < 2; ++k) {
    int id = t + k * 256;
    int r = id >> 5, f4 = id & 31;
    float4 v = *(const float4*)(seq + (size_t)(row0 + r) * F_ + f4 * 4);
    *(float4*)&st[r * 132 + f4 * 4] = v;
  }
  __syncthreads();
  const int r0 = wv * 4;
  float acc[4] = {0.f, 0.f, 0.f, 0.f};
#pragma unroll 8
  for (int f = 0; f < F_; ++f) {
    float e = ew[f * U_ + lane];
#pragma unroll
    for (int r = 0; r < 4; ++r)
      acc[r] = fmaf(st[(r0 + r) * 132 + f], e, acc[r]);
  }
#pragma unroll
  for (int r = 0; r < 4; ++r)
    beta[(size_t)(row0 + r0 + r) * U_ + lane] = acc[r];
}

// -------------------------------------------------------------------------
// k_alpha v4: out[b,n,m,u] = sum_f seq[b,n,f]*vw[f,m,u] (pre-activation).
// grid 512 (8 rows/block, 2 blocks/CU), block 256.
// Thread: q = t&15 -> u0=q*4; g = t>>4 -> r = g&7, mh = g>>3 (m = mh*4+mm).
// Per f: 1 LDS broadcast (s) + 4 float4 vw loads (16 distinct addrs/wave
// = 256 B/inst, L2-hot) + 16 FMA. ~5-8 us.
// -------------------------------------------------------------------------
__global__ __launch_bounds__(256, 2) void k_alpha(const float* __restrict__ seq,
                                                  const float* __restrict__ vw,
                                                  float* __restrict__ out) {
  __shared__ float ss[8 * 128];
  const int t    = threadIdx.x;
  const int q    = t & 15;
  const int g    = t >> 4;
  const int r    = g & 7;
  const int mh   = g >> 3;
  const int row0 = blockIdx.x * 8;

  // stage seq rows: 8*128 floats = 256 float4 -> 1 per thread, coalesced
  {
    float4 v = *(const float4*)(seq + (size_t)row0 * F_ + t * 4);
    *(float4*)&ss[t * 4] = v;
  }
  __syncthreads();

  float acc[4][4] = {};  // [mm][uu]
  const float* wbase = vw + mh * 4 * 64 + q * 4;
#pragma unroll 4
  for (int f = 0; f < F_; ++f) {
    float s = ss[r * F_ + f];
    const float* wf = wbase + (size_t)f * 512;
#pragma unroll
    for (int mm = 0; mm < 4; ++mm) {
      float4 wv = *(const float4*)(wf + mm * 64);
      acc[mm][0] = fmaf(s, wv.x, acc[mm][0]);
      acc[mm][1] = fmaf(s, wv.y, acc[mm][1]);
      acc[mm][2] = fmaf(s, wv.z, acc[mm][2]);
      acc[mm][3] = fmaf(s, wv.w, acc[mm][3]);
    }
  }
  float* o = out + (size_t)(row0 + r) * 512 + mh * 4 * 64 + q * 4;
#pragma unroll
  for (int mm = 0; mm < 4; ++mm) {
    float4 res;
    res.x = acc[mm][0]; res.y = acc[mm][1];
    res.z = acc[mm][2]; res.w = acc[mm][3];
    *(float4*)(o + mm * 64) = res;
  }
}

// -------------------------------------------------------------------------
// k_main v4: C[r=i*8+m][u] = sum_j graph[b,i,j,m]*beta[b,j,u], + alpha,
// sigmoid. Block 64r x 64u, 256 thr, grid 512.
//
// Round-4 fix: EXPLICIT register double-buffered A pipeline. Batches of
// 8 j: load batch n+1 into the idle buffer while FMA-ing batch n ->
// 8-16 loads in flight per wave (fine-grained vmcnt), vs ~2 before
// (VGPR_Count=60 showed the compiler serialized). Batch 0 issued before
// the staging barrier to overlap with B-tile staging latency.
// LDS pad dropped (inner read = 4 distinct b128 over 16 banks, 16-way
// broadcast — conflict-free without pad). VGPR budget ~110 (cap 128).
// -------------------------------------------------------------------------
__global__ __launch_bounds__(256, 2) void k_main(const float* __restrict__ graph,
                                                 const float* __restrict__ beta,
                                                 float* __restrict__ out) {
  __shared__ float Bt[128 * 64];  // 32768 B
  const int t    = threadIdx.x;
  const int w    = t >> 6;
  const int lane = t & 63;
  const int rr   = lane >> 2;   // 0..15
  const int uq   = lane & 3;    // 0..3
  const int i_loc = rr >> 1;    // 0..7
  const int mh    = rr & 1;     // 0..1
  const int u0    = w * 16 + uq * 4;

  const int bx = blockIdx.x;
  const int b  = bx >> 8;
  const int rb = bx & 255;
  const int i  = rb * 8 + i_loc;

  const float* gp = graph + ((size_t)(b * N_ + i) * N_) * M_ + mh * 4;
  const float* bp = beta + (size_t)b * N_ * U_;

  float acc[4][4] = {};  // [mm][uu]
  float4 a0[8], a1[8];

#define FMA16(AV, BV)                                                   \
  do {                                                                  \
    acc[0][0] = fmaf((AV).x, (BV).x, acc[0][0]);                        \
    acc[0][1] = fmaf((AV).x, (BV).y, acc[0][1]);                        \
    acc[0][2] = fmaf((AV).x, (BV).z, acc[0][2]);                        \
    acc[0][3] = fmaf((AV).x, (BV).w, acc[0][3]);                        \
    acc[1][0] = fmaf((AV).y, (BV).x, acc[1][0]);                        \
    acc[1][1] = fmaf((AV).y, (BV).y, acc[1][1]);                        \
    acc[1][2] = fmaf((AV).y, (BV).z, acc[1][2]);                        \
    acc[1][3] = fmaf((AV).y, (BV).w, acc[1][3]);                        \
    acc[2][0] = fmaf((AV).z, (BV).x, acc[2][0]);                        \
    acc[2][1] = fmaf((AV).z, (BV).y, acc[2][1]);                        \
    acc[2][2] = fmaf((AV).z, (BV).z, acc[2][2]);                        \
    acc[2][3] = fmaf((AV).z, (BV).w, acc[2][3]);                        \
    acc[3][0] = fmaf((AV).w, (BV).x, acc[3][0]);                        \
    acc[3][1] = fmaf((AV).w, (BV).y, acc[3][1]);                        \
    acc[3][2] = fmaf((AV).w, (BV).z, acc[3][2]);                        \
    acc[3][3] = fmaf((AV).w, (BV).w, acc[3][3]);                        \
  } while (0)

#pragma unroll 1
  for (int c = 0; c < 16; ++c) {
    const int j0 = c * 128;
    const float* gc = gp + (size_t)j0 * M_;
    __syncthreads();  // previous-chunk readers done before overwrite
    // stage B tile: beta[j0..j0+128][0..64] is one contiguous 32 KB block
#pragma unroll
    for (int k = 0; k < 8; ++k) {
      int id = t + k * 256;
      float4 v = *(const float4*)(bp + (size_t)j0 * U_ + id * 4);
      *(float4*)&Bt[id * 4] = v;
    }
    // prefetch A batch 0 of this chunk (LDS-independent; overlaps staging)
#pragma unroll
    for (int jj = 0; jj < 8; ++jj)
      a0[jj] = *(const float4*)(gc + jj * M_);
    __syncthreads();

#pragma unroll 1
    for (int jb = 0; jb < 16; jb += 2) {
      // prefetch batch jb+1 -> a1 (in flight during a0 consumption)
#pragma unroll
      for (int jj = 0; jj < 8; ++jj)
        a1[jj] = *(const float4*)(gc + (size_t)((jb + 1) * 8 + jj) * M_);
      // consume batch jb (a0)
#pragma unroll
      for (int jj = 0; jj < 8; ++jj) {
        const int j = jb * 8 + jj;
        float4 bv = *(const float4*)&Bt[j * 64 + u0];
        FMA16(a0[jj], bv);
      }
      // prefetch batch (jb+2)&15 -> a0 (wrap on last: harmless L1-hot reload)
      const int jn = (jb + 2) & 15;
#pragma unroll
      for (int jj = 0; jj < 8; ++jj)
        a0[jj] = *(const float4*)(gc + (size_t)(jn * 8 + jj) * M_);
      // consume batch jb+1 (a1)
#pragma unroll
      for (int jj = 0; jj < 8; ++jj) {
        const int j = (jb + 1) * 8 + jj;
        float4 bv = *(const float4*)&Bt[j * 64 + u0];
        FMA16(a1[jj], bv);
      }
    }
  }

  // Epilogue: row = rb*64 + i_loc*8 + mh*4 + mm; add alpha (in d_out), sigmoid
  float* o = out + ((size_t)(b * 16384 + rb * 64 + i_loc * 8 + mh * 4)) * U_ + u0;
#pragma unroll
  for (int mm = 0; mm < 4; ++mm) {
    float4 al = *(float4*)(o + (size_t)mm * U_);
    float4 res;
    res.x = 1.0f / (1.0f + __expf(-(acc[mm][0] + al.x)));
    res.y = 1.0f / (1.0f + __expf(-(acc[mm][1] + al.y)));
    res.z = 1.0f / (1.0f + __expf(-(acc[mm][2] + al.z)));
    res.w = 1.0f / (1.0f + __expf(-(acc[mm][3] + al.w)));
    *(float4*)(o + (size_t)mm * U_) = res;
  }
#undef FMA16
}

// -------------------------------------------------------------------------
extern "C" void kernel_launch(void* const* d_in, const int* in_sizes, int n_in,
                              void* d_out, int out_size, void* d_ws, size_t ws_size,
                              hipStream_t stream) {
  const float* seq   = (const float*)d_in[0];  // (B,N,F)
  const float* graph = (const float*)d_in[1];  // (B,N,N,M)
  const float* ew    = (const float*)d_in[2];  // (F,U)
  const float* vw    = (const float*)d_in[3];  // (F,M,U)
  float* out  = (float*)d_out;                 // (B,N,M,U)
  float* beta = (float*)d_ws;                  // [B][N][U] = 1 MB scratch

  hipLaunchKernelGGL(k_beta,  dim3(256), dim3(256), 0, stream, seq, ew, beta);
  hipLaunchKernelGGL(k_alpha, dim3(512), dim3(256), 0, stream, seq, vw, out);
  hipLaunchKernelGGL(k_main,  dim3(512), dim3(256), 0, stream, graph, beta, out);
}

// Round 5
// 410.337 us; speedup vs baseline: 1.6442x; 1.3234x over previous
//
#include <hip/hip_runtime.h>
#include <cmath>

// (B, N, F_IN, M, U) = (2, 2048, 128, 8, 64)
#define N_ 2048
#define F_ 128
#define M_ 8
#define U_ 64

typedef _Float16 f16;
typedef _Float16 f16x2 __attribute__((ext_vector_type(2)));
typedef _Float16 f16x8 __attribute__((ext_vector_type(8)));
typedef float f32x4 __attribute__((ext_vector_type(4)));

#define BK 32   // K-chunk (j) per stage
#define RS 40   // LDS row stride in fp16 (BK + 8 pad; 80 B, 16-B aligned)

// -------------------------------------------------------------------------
// k_beta: beta[b][n][u] = sum_f seq[b,n,f] * ew[f,u], computed fp32, stored
// SPLIT-fp16 TRANSPOSED: bh/bl[b][u][n] (k-major for k_main's B fragments).
// hi = rn(v), lo = rn(v - hi) -> hi+lo == v to ~2^-24 rel.
// grid 256, block 256. Scalar b16 stores are scattered but beta is tiny.
// -------------------------------------------------------------------------
__global__ __launch_bounds__(256) void k_beta(const float* __restrict__ seq,
                                              const float* __restrict__ ew,
                                              f16* __restrict__ bh,
                                              f16* __restrict__ bl) {
  __shared__ float st[16 * 132];
  const int t    = threadIdx.x;
  const int lane = t & 63;
  const int wv   = t >> 6;
  const int row0 = blockIdx.x * 16;
#pragma unroll
  for (int k = 0; k < 2; ++k) {
    int id = t + k * 256;
    int r = id >> 5, f4 = id & 31;
    float4 v = *(const float4*)(seq + (size_t)(row0 + r) * F_ + f4 * 4);
    *(float4*)&st[r * 132 + f4 * 4] = v;
  }
  __syncthreads();
  const int r0 = wv * 4;
  float acc[4] = {0.f, 0.f, 0.f, 0.f};
#pragma unroll 8
  for (int f = 0; f < F_; ++f) {
    float e = ew[f * U_ + lane];
#pragma unroll
    for (int r = 0; r < 4; ++r)
      acc[r] = fmaf(st[(r0 + r) * 132 + f], e, acc[r]);
  }
#pragma unroll
  for (int r = 0; r < 4; ++r) {
    int row = row0 + r0 + r;
    int b = row >> 11, n = row & (N_ - 1);
    float v = acc[r];
    f16 h = (f16)v;
    f16 l = (f16)(v - (float)h);
    size_t idx = ((size_t)(b * U_ + lane)) * N_ + n;  // [b][u][n]
    bh[idx] = h;
    bl[idx] = l;
  }
}

// -------------------------------------------------------------------------
// k_alpha: out[b,n,m,u] = sum_f seq[b,n,f]*vw[f,m,u] (fp32 pre-activation
// into d_out; k_main adds graph term + sigmoid). Unchanged from round 4.
// -------------------------------------------------------------------------
__global__ __launch_bounds__(256, 2) void k_alpha(const float* __restrict__ seq,
                                                  const float* __restrict__ vw,
                                                  float* __restrict__ out) {
  __shared__ float ss[8 * 128];
  const int t    = threadIdx.x;
  const int q    = t & 15;
  const int g    = t >> 4;
  const int r    = g & 7;
  const int mh   = g >> 3;
  const int row0 = blockIdx.x * 8;
  {
    float4 v = *(const float4*)(seq + (size_t)row0 * F_ + t * 4);
    *(float4*)&ss[t * 4] = v;
  }
  __syncthreads();
  float acc[4][4] = {};
  const float* wbase = vw + mh * 4 * 64 + q * 4;
#pragma unroll 4
  for (int f = 0; f < F_; ++f) {
    float s = ss[r * F_ + f];
    const float* wf = wbase + (size_t)f * 512;
#pragma unroll
    for (int mm = 0; mm < 4; ++mm) {
      float4 wv = *(const float4*)(wf + mm * 64);
      acc[mm][0] = fmaf(s, wv.x, acc[mm][0]);
      acc[mm][1] = fmaf(s, wv.y, acc[mm][1]);
      acc[mm][2] = fmaf(s, wv.z, acc[mm][2]);
      acc[mm][3] = fmaf(s, wv.w, acc[mm][3]);
    }
  }
  float* o = out + (size_t)(row0 + r) * 512 + mh * 4 * 64 + q * 4;
#pragma unroll
  for (int mm = 0; mm < 4; ++mm) {
    float4 res;
    res.x = acc[mm][0]; res.y = acc[mm][1];
    res.z = acc[mm][2]; res.w = acc[mm][3];
    *(float4*)(o + mm * 64) = res;
  }
}

// -------------------------------------------------------------------------
// k_main v5 (MFMA): per batch, C[r=i*8+m][u] = sum_j A[r][j]*B[j][u];
// A = graph slice (fp32 -> split fp16 hi/lo on the fly), B = split-fp16
// beta (k-major from k_beta). mfma_f32_16x16x32_f16, 3 MFMA/tile
// (hi*hi + lo*hi + hi*lo) => fp32-exact to ~1e-5.
//
// Block: 64 r x 64 u, 256 thr (4 waves); wave w owns r-tile w (16 rows),
// all 4 u-tiles; acc = 4 x f32x4. K-chunks of 32 j, LDS double-buffered
// (Ah/Al/Bh/Bl x2 = 40 KB). Pipeline per chunk: compute(buf) ->
// cvt+write(buf^1 from regs) -> load(chunk+2 into regs) -> barrier:
// global loads stay in flight across an entire compute phase by
// construction (not compiler goodwill). HBM floor: 268 MB / 6.3 TB/s
// = 43 us. Grid 512 = 2 blocks/CU, 8 waves/CU.
//
// Layouts (HW-verified facts): A-frag A[m=lane&15][k=(lane>>4)*8+j],
// B-frag B[k=(lane>>4)*8+j][n=lane&15], C/D col=lane&15,
// row=(lane>>4)*4+reg. LDS row stride RS=40 fp16 -> b128 frag reads at
// baseline rate; staging writes <=2-way (free).
// -------------------------------------------------------------------------
__global__ __launch_bounds__(256, 2) void k_main(const float* __restrict__ graph,
                                                 const f16* __restrict__ betah,
                                                 const f16* __restrict__ betal,
                                                 float* __restrict__ out) {
  __shared__ f16 Ah[2][64 * RS];
  __shared__ f16 Al[2][64 * RS];
  __shared__ f16 Bh[2][64 * RS];
  __shared__ f16 Bl[2][64 * RS];

  const int t    = threadIdx.x;
  const int w    = t >> 6;
  const int lane = t & 63;
  const int l15  = lane & 15;
  const int quad = lane >> 4;

  const int bx = blockIdx.x;
  const int b  = bx >> 8;
  const int rb = bx & 255;        // 64-row tile; i0 = rb*8

  // staging decode: A: thread -> (i_loc, j-pair, m-half); B: (u-row, j-part)
  const int iA = t >> 5;          // 0..7
  const int r5 = t & 31;
  const int jp = r5 >> 1;         // 0..15
  const int mh = r5 & 1;          // 0..1
  const int uB = t >> 2;          // 0..63
  const int pB = t & 3;           // 0..3

  const float* gA = graph + ((size_t)(b * N_ + rb * 8 + iA)) * (N_ * M_) + mh * 4;
  const f16* bhp = betah + ((size_t)(b * U_ + uB)) * N_ + pB * 8;
  const f16* blp = betal + ((size_t)(b * U_ + uB)) * N_ + pB * 8;

  f32x4 acc[4] = {f32x4{0.f, 0.f, 0.f, 0.f}, f32x4{0.f, 0.f, 0.f, 0.f},
                  f32x4{0.f, 0.f, 0.f, 0.f}, f32x4{0.f, 0.f, 0.f, 0.f}};

  float4 ra0, ra1;                // graph (j, j+1) x 4 m
  uint4 rbh, rbl;                 // beta hi/lo, 8 fp16 each

#define LOADC(c)                                                          \
  do {                                                                    \
    const float* g_ = gA + (size_t)((c) * BK + jp * 2) * M_;              \
    ra0 = *(const float4*)g_;                                             \
    ra1 = *(const float4*)(g_ + M_);                                      \
    rbh = *(const uint4*)(bhp + (c) * BK);                                \
    rbl = *(const uint4*)(blp + (c) * BK);                                \
  } while (0)

#define WRITEC(buf)                                                       \
  do {                                                                    \
    float g0s[4] = {ra0.x, ra0.y, ra0.z, ra0.w};                          \
    float g1s[4] = {ra1.x, ra1.y, ra1.z, ra1.w};                          \
    _Pragma("unroll") for (int mw = 0; mw < 4; ++mw) {                    \
      float g0 = g0s[mw], g1 = g1s[mw];                                   \
      f16 h0 = (f16)g0, h1 = (f16)g1;                                     \
      f16 l0 = (f16)(g0 - (float)h0), l1 = (f16)(g1 - (float)h1);         \
      int r_ = iA * 8 + mh * 4 + mw;                                      \
      f16x2 hv; hv[0] = h0; hv[1] = h1;                                   \
      f16x2 lv; lv[0] = l0; lv[1] = l1;                                   \
      *(f16x2*)&Ah[buf][r_ * RS + jp * 2] = hv;                           \
      *(f16x2*)&Al[buf][r_ * RS + jp * 2] = lv;                           \
    }                                                                     \
    *(uint4*)&Bh[buf][uB * RS + pB * 8] = rbh;                            \
    *(uint4*)&Bl[buf][uB * RS + pB * 8] = rbl;                            \
  } while (0)

#define COMPUTE(buf)                                                      \
  do {                                                                    \
    const int ab_ = (w * 16 + l15) * RS + quad * 8;                       \
    f16x8 ah = *(const f16x8*)&Ah[buf][ab_];                              \
    f16x8 al = *(const f16x8*)&Al[buf][ab_];                              \
    _Pragma("unroll") for (int ut = 0; ut < 4; ++ut) {                    \
      const int bb_ = (ut * 16 + l15) * RS + quad * 8;                    \
      f16x8 bhf = *(const f16x8*)&Bh[buf][bb_];                           \
      f16x8 blf = *(const f16x8*)&Bl[buf][bb_];                           \
      acc[ut] = __builtin_amdgcn_mfma_f32_16x16x32_f16(ah, bhf, acc[ut], 0, 0, 0); \
      acc[ut] = __builtin_amdgcn_mfma_f32_16x16x32_f16(al, bhf, acc[ut], 0, 0, 0); \
      acc[ut] = __builtin_amdgcn_mfma_f32_16x16x32_f16(ah, blf, acc[ut], 0, 0, 0); \
    }                                                                     \
  } while (0)

  LOADC(0);
  WRITEC(0);
  LOADC(1);                       // in flight across first compute
  __syncthreads();

#pragma unroll 2
  for (int c = 0; c < N_ / BK; ++c) {
    COMPUTE(c & 1);
    if (c < N_ / BK - 1) {
      WRITEC((c + 1) & 1);        // waits vmcnt; buffer's last readers done
      if (c < N_ / BK - 2) LOADC(c + 2);
      __syncthreads();
    }
  }

  // Epilogue: C row = rb*64 + w*16 + quad*4 + reg, col u = ut*16 + l15.
  const int rowbase = rb * 64 + w * 16 + quad * 4;
#pragma unroll
  for (int ut = 0; ut < 4; ++ut) {
    const int u = ut * 16 + l15;
#pragma unroll
    for (int reg = 0; reg < 4; ++reg) {
      size_t idx = ((size_t)(b * 16384 + rowbase + reg)) * U_ + u;
      float x = acc[ut][reg] + out[idx];
      out[idx] = 1.0f / (1.0f + __expf(-x));
    }
  }
#undef LOADC
#undef WRITEC
#undef COMPUTE
}

// -------------------------------------------------------------------------
extern "C" void kernel_launch(void* const* d_in, const int* in_sizes, int n_in,
                              void* d_out, int out_size, void* d_ws, size_t ws_size,
                              hipStream_t stream) {
  const float* seq   = (const float*)d_in[0];  // (B,N,F)
  const float* graph = (const float*)d_in[1];  // (B,N,N,M)
  const float* ew    = (const float*)d_in[2];  // (F,U)
  const float* vw    = (const float*)d_in[3];  // (F,M,U)
  float* out = (float*)d_out;                  // (B,N,M,U)

  f16* betah = (f16*)d_ws;                     // [B][U][N] fp16 hi = 512 KB
  f16* betal = betah + (size_t)2 * U_ * N_;    // [B][U][N] fp16 lo = 512 KB

  hipLaunchKernelGGL(k_beta,  dim3(256), dim3(256), 0, stream, seq, ew, betah, betal);
  hipLaunchKernelGGL(k_alpha, dim3(512), dim3(256), 0, stream, seq, vw, out);
  hipLaunchKernelGGL(k_main,  dim3(512), dim3(256), 0, stream, graph, betah, betal, out);
}